// Round 7
// baseline (38.764 us; speedup 1.0000x reference)
//
#include <hip/hip_runtime.h>
#include <hip/hip_bf16.h>

#define E 1024
#define F 12

typedef float f32x4 __attribute__((ext_vector_type(4)));

// DPP add: v += dpp(v). 0x110|N = row_shr:N within 16-lane row, bound_ctrl 0-fill.
template<int CTRL>
__device__ __forceinline__ float dpp_add(float v) {
    int x = __builtin_amdgcn_update_dpp(0, __float_as_int(v), CTRL, 0xf, 0xf, true);
    return v + __int_as_float(x);
}
// 4-stage reduce within each 16-lane group; lane 15 (mod 16) holds the group sum.
__device__ __forceinline__ float group16_sum(float v) {
    v = dpp_add<0x111>(v);
    v = dpp_add<0x112>(v);
    v = dpp_add<0x114>(v);
    v = dpp_add<0x118>(v);
    return v;
}

// ---------------- Kernel A: q[row][12] = cos(relu(x.W1^T + b1) + theta) ------
// One block per 4 rows; 4096 blocks -> latency hidden by block parallelism.
__global__ __launch_bounds__(256) void ffq_qgen(
    const float* __restrict__ x,
    const float* __restrict__ W1,
    const float* __restrict__ b1,
    const float* __restrict__ theta,
    float* __restrict__ qout,
    int nrows)
{
    const int tid  = threadIdx.x;
    const int lane = tid & 63;
    const int wave = tid >> 6;
    const int grp  = lane >> 4;
    const int fi   = lane & 15;

    const int rstart = blockIdx.x * 4;
    if (rstart >= nrows) return;

    // issue x loads first (HBM); W1 loads are L2/L3 hits after the first blocks
    f32x4 xv[4];
#pragma unroll
    for (int r = 0; r < 4; ++r)
        if (rstart + r < nrows)
            xv[r] = *reinterpret_cast<const f32x4*>(x + (size_t)(rstart + r) * E + tid * 4);

    f32x4 w1[F];
#pragma unroll
    for (int f = 0; f < F; ++f)
        w1[f] = *reinterpret_cast<const f32x4*>(W1 + f * E + tid * 4);

    float b1r = 0.f, thr = 0.f;
    if (fi < F) { b1r = b1[fi]; thr = theta[fi]; }

    __shared__ __align__(16) float red[4][4][4][16];   // [wave][grp][r][f(pad16)]

#pragma unroll
    for (int r = 0; r < 4; ++r) {
        float part[F];
#pragma unroll
        for (int f = 0; f < F; ++f) {
            part[f] = fmaf(xv[r].x, w1[f].x,
                      fmaf(xv[r].y, w1[f].y,
                      fmaf(xv[r].z, w1[f].z, xv[r].w * w1[f].w)));
        }
#pragma unroll
        for (int f = 0; f < F; ++f) part[f] = group16_sum(part[f]);

        if (fi == 15) {
#pragma unroll
            for (int qq = 0; qq < 3; ++qq) {
                f32x4 v = { part[4*qq], part[4*qq+1], part[4*qq+2], part[4*qq+3] };
                *reinterpret_cast<f32x4*>(&red[wave][grp][r][4 * qq]) = v;
            }
        }
    }
    __syncthreads();

    // finisher: 48 lanes (r = tid>>4, f = tid&15), scalar store of q
    if (tid < 64 && fi < F) {
        const int r = tid >> 4;
        if (rstart + r < nrows) {
            float s = b1r;
#pragma unroll
            for (int w = 0; w < 4; ++w)
#pragma unroll
                for (int g = 0; g < 4; ++g)
                    s += red[w][g][r][fi];
            qout[(size_t)(rstart + r) * F + fi] = __cosf(fmaxf(s, 0.0f) + thr);
        }
    }
}

// ---------------- Kernel B: out[row][e] = q[row].W2[e] + b2[e] ---------------
// Pure streaming: no barriers, no LDS, no reductions. Store-bound.
#define ROWS_B 16
__global__ __launch_bounds__(256) void ffq_expand(
    const float* __restrict__ q,
    const float* __restrict__ W2,
    const float* __restrict__ b2,
    float* __restrict__ out,
    int nrows)
{
    const int tid = threadIdx.x;

    float w2l[48];                 // W2[(4t+j)][f] = w2l[12j+f]
#pragma unroll
    for (int k = 0; k < 12; ++k)
        *reinterpret_cast<f32x4*>(&w2l[4 * k]) =
            *reinterpret_cast<const f32x4*>(W2 + tid * 48 + 4 * k);

    const f32x4 bias2 = *reinterpret_cast<const f32x4*>(b2 + tid * 4);

    const int rstart = blockIdx.x * ROWS_B;
    if (rstart >= nrows) return;
    const int rend = min(rstart + ROWS_B, nrows);

    // q rows are 48 B (16B-aligned); wave-uniform loads -> scalar cache
    f32x4 q0 = *reinterpret_cast<const f32x4*>(q + (size_t)rstart * F + 0);
    f32x4 q1 = *reinterpret_cast<const f32x4*>(q + (size_t)rstart * F + 4);
    f32x4 q2 = *reinterpret_cast<const f32x4*>(q + (size_t)rstart * F + 8);

    for (int row = rstart; row < rend; ++row) {
        f32x4 n0, n1, n2;
        if (row + 1 < rend) {
            n0 = *reinterpret_cast<const f32x4*>(q + (size_t)(row + 1) * F + 0);
            n1 = *reinterpret_cast<const f32x4*>(q + (size_t)(row + 1) * F + 4);
            n2 = *reinterpret_cast<const f32x4*>(q + (size_t)(row + 1) * F + 8);
        }
        float qf[F];
        *reinterpret_cast<f32x4*>(&qf[0]) = q0;
        *reinterpret_cast<f32x4*>(&qf[4]) = q1;
        *reinterpret_cast<f32x4*>(&qf[8]) = q2;

        f32x4 o;
#pragma unroll
        for (int j = 0; j < 4; ++j) {
            float acc = bias2[j];
#pragma unroll
            for (int f = 0; f < F; ++f) acc = fmaf(qf[f], w2l[12 * j + f], acc);
            o[j] = acc;
        }
        __builtin_nontemporal_store(o,
            reinterpret_cast<f32x4*>(out + (size_t)row * E + tid * 4));

        q0 = n0; q1 = n1; q2 = n2;
    }
}

// ---------------- Fallback: proven fused kernel (R3) if ws too small ---------
__device__ __forceinline__ float wave_sum_lane63(float v) {
    v = dpp_add<0x111>(v);
    v = dpp_add<0x112>(v);
    v = dpp_add<0x114>(v);
    v = dpp_add<0x118>(v);
    v = dpp_add<0x142>(v);
    v = dpp_add<0x143>(v);
    return v;
}

__global__ __launch_bounds__(256, 2) void ffq_fused(
    const float* __restrict__ x,
    const float* __restrict__ W1,
    const float* __restrict__ b1,
    const float* __restrict__ theta,
    const float* __restrict__ W2,
    const float* __restrict__ b2,
    float* __restrict__ out,
    int nrows, int rows_per_block)
{
    const int tid  = threadIdx.x;
    const int lane = tid & 63;
    const int wave = tid >> 6;

    f32x4 w1[F];
#pragma unroll
    for (int f = 0; f < F; ++f)
        w1[f] = *reinterpret_cast<const f32x4*>(W1 + f * E + tid * 4);
    float w2l[48];
#pragma unroll
    for (int k = 0; k < 12; ++k)
        *reinterpret_cast<f32x4*>(&w2l[4 * k]) =
            *reinterpret_cast<const f32x4*>(W2 + tid * 48 + 4 * k);
    const f32x4 bias2 = *reinterpret_cast<const f32x4*>(b2 + tid * 4);
    float b1r = 0.f, thr = 0.f;
    if (tid < 64 && (tid & 15) < F) { b1r = b1[tid & 15]; thr = theta[tid & 15]; }

    __shared__ __align__(16) float red[4][4][F];
    __shared__ __align__(16) float qsh[4][F];

    const int rstart = blockIdx.x * rows_per_block;
    const int rend   = min(rstart + rows_per_block, nrows);
    if (rstart >= rend) return;

    f32x4 xv[4], xn[4];
#pragma unroll
    for (int r = 0; r < 4; ++r)
        if (rstart + r < rend)
            xv[r] = *reinterpret_cast<const f32x4*>(x + (size_t)(rstart + r) * E + tid * 4);

    for (int base = rstart; base < rend; base += 4) {
        float part[4][F];
#pragma unroll
        for (int r = 0; r < 4; ++r)
#pragma unroll
            for (int f = 0; f < F; ++f)
                part[r][f] = fmaf(xv[r].x, w1[f].x,
                             fmaf(xv[r].y, w1[f].y,
                             fmaf(xv[r].z, w1[f].z, xv[r].w * w1[f].w)));
#pragma unroll
        for (int r = 0; r < 4; ++r)
            if (base + 4 + r < rend)
                xn[r] = *reinterpret_cast<const f32x4*>(x + (size_t)(base + 4 + r) * E + tid * 4);
#pragma unroll
        for (int r = 0; r < 4; ++r)
#pragma unroll
            for (int f = 0; f < F; ++f)
                part[r][f] = wave_sum_lane63(part[r][f]);

        if (lane == 63) {
#pragma unroll
            for (int r = 0; r < 4; ++r) {
                f32x4 a = { part[r][0], part[r][1], part[r][2],  part[r][3] };
                f32x4 b = { part[r][4], part[r][5], part[r][6],  part[r][7] };
                f32x4 c = { part[r][8], part[r][9], part[r][10], part[r][11] };
                *reinterpret_cast<f32x4*>(&red[wave][r][0]) = a;
                *reinterpret_cast<f32x4*>(&red[wave][r][4]) = b;
                *reinterpret_cast<f32x4*>(&red[wave][r][8]) = c;
            }
        }
        __syncthreads();
        if (tid < 64 && (tid & 15) < F) {
            const int r = tid >> 4, fi2 = tid & 15;
            if (base + r < rend) {
                float d = red[0][r][fi2] + red[1][r][fi2] + red[2][r][fi2] + red[3][r][fi2] + b1r;
                qsh[r][fi2] = __cosf(fmaxf(d, 0.0f) + thr);
            }
        }
        __syncthreads();
#pragma unroll
        for (int r = 0; r < 4; ++r) {
            if (base + r < rend) {
                float qf[F];
                *reinterpret_cast<f32x4*>(&qf[0]) = *reinterpret_cast<const f32x4*>(&qsh[r][0]);
                *reinterpret_cast<f32x4*>(&qf[4]) = *reinterpret_cast<const f32x4*>(&qsh[r][4]);
                *reinterpret_cast<f32x4*>(&qf[8]) = *reinterpret_cast<const f32x4*>(&qsh[r][8]);
                f32x4 o;
#pragma unroll
                for (int j = 0; j < 4; ++j) {
                    float acc = bias2[j];
#pragma unroll
                    for (int f = 0; f < F; ++f) acc = fmaf(qf[f], w2l[12 * j + f], acc);
                    o[j] = acc;
                }
                __builtin_nontemporal_store(o,
                    reinterpret_cast<f32x4*>(out + (size_t)(base + r) * E + tid * 4));
            }
        }
#pragma unroll
        for (int r = 0; r < 4; ++r) xv[r] = xn[r];
    }
}

extern "C" void kernel_launch(void* const* d_in, const int* in_sizes, int n_in,
                              void* d_out, int out_size, void* d_ws, size_t ws_size,
                              hipStream_t stream)
{
    const float* x     = (const float*)d_in[0];
    const float* W1    = (const float*)d_in[1];
    const float* b1    = (const float*)d_in[2];
    const float* theta = (const float*)d_in[3];
    const float* W2    = (const float*)d_in[4];
    const float* b2    = (const float*)d_in[5];
    float* out = (float*)d_out;

    const int nrows = in_sizes[0] / E;                 // B*S = 16384
    const size_t q_bytes = (size_t)nrows * F * sizeof(float);

    if (ws_size >= q_bytes) {
        float* q = (float*)d_ws;
        const int gridA = (nrows + 3) / 4;             // 4096
        ffq_qgen<<<gridA, 256, 0, stream>>>(x, W1, b1, theta, q, nrows);
        const int gridB = (nrows + ROWS_B - 1) / ROWS_B;  // 1024
        ffq_expand<<<gridB, 256, 0, stream>>>(q, W2, b2, out, nrows);
    } else {
        const int rpb  = 16;
        const int grid = (nrows + rpb - 1) / rpb;
        ffq_fused<<<grid, 256, 0, stream>>>(x, W1, b1, theta, W2, b2, out, nrows, rpb);
    }
}

// Round 8
// 29.516 us; speedup vs baseline: 1.3133x; 1.3133x over previous
//
#include <hip/hip_runtime.h>
#include <hip/hip_bf16.h>

#define E 1024
#define F 12
#define BM 16   // rows per block

typedef float f32x4_t __attribute__((ext_vector_type(4)));
typedef short bf16x8  __attribute__((ext_vector_type(8)));

// float -> bf16 bits (RNE); scalar cast lets the compiler emit v_cvt_pk_bf16_f32 pairs
__device__ __forceinline__ short f2bf(float f) {
    return (short)__builtin_bit_cast(unsigned short, __float2bfloat16(f));
}

__global__ __launch_bounds__(256, 4) void ffq_mfma(
    const float* __restrict__ x,
    const float* __restrict__ W1,
    const float* __restrict__ b1,
    const float* __restrict__ theta,
    const float* __restrict__ W2,
    const float* __restrict__ b2,
    float* __restrict__ out, int nrows)
{
    const int tid  = threadIdx.x;
    const int lane = tid & 63;
    const int wave = tid >> 6;     // K-split: wave w covers k in [w*256, (w+1)*256)
    const int g    = lane >> 4;    // k sub-group within the fragment
    const int n    = lane & 15;    // MFMA: A row (m) / B col (f) / C col

    const int row0 = blockIdx.x * BM;
    if (row0 >= nrows) return;

    __shared__ __align__(16) float red[4][64][4];  // per-wave partial C
    __shared__ __align__(16) float qsh[16][20];    // q[m][f], padded row=80B (16B-aligned)

    // ---------------- phase 1: h = x . W1^T via MFMA ----------------
    // A slot (g,j) <- x[row0+n][kb + g*8 + j]; B slot (g,j) <- W1[nc][kb + g*8 + j].
    // Same (g,j)->k map for A and B => HW pairs them correctly (any bijection works).
    const int nc = (n < F) ? n : (F - 1);            // clamp: C cols 12..15 unused
    const int mrow = min(row0 + n, nrows - 1);
    const float* xrow = x  + (size_t)mrow * E + wave * 256 + g * 8;
    const float* wrow = W1 + (size_t)nc   * E + wave * 256 + g * 8;

    f32x4_t acc0 = {0.f, 0.f, 0.f, 0.f}, acc1 = {0.f, 0.f, 0.f, 0.f};
#pragma unroll
    for (int ks = 0; ks < 8; ++ks) {
        f32x4_t a0 = *reinterpret_cast<const f32x4_t*>(xrow + ks * 32);
        f32x4_t a1 = *reinterpret_cast<const f32x4_t*>(xrow + ks * 32 + 4);
        f32x4_t b0 = *reinterpret_cast<const f32x4_t*>(wrow + ks * 32);
        f32x4_t b1v= *reinterpret_cast<const f32x4_t*>(wrow + ks * 32 + 4);
        bf16x8 af, bfr;
#pragma unroll
        for (int j = 0; j < 4; ++j) {
            af[j]      = f2bf(a0[j]);
            af[j + 4]  = f2bf(a1[j]);
            bfr[j]     = f2bf(b0[j]);
            bfr[j + 4] = f2bf(b1v[j]);
        }
        if (ks & 1) acc1 = __builtin_amdgcn_mfma_f32_16x16x32_bf16(af, bfr, acc1, 0, 0, 0);
        else        acc0 = __builtin_amdgcn_mfma_f32_16x16x32_bf16(af, bfr, acc0, 0, 0, 0);
    }
    *reinterpret_cast<f32x4_t*>(&red[wave][lane][0]) = acc0 + acc1;

    __syncthreads();   // the only block barrier

    // ---- W2/bias loads AFTER barrier: live range doesn't overlap phase1 staging ----
    float w2l[48];                 // W2[(4t+j)][f] = w2l[12j+f]
#pragma unroll
    for (int k2 = 0; k2 < 12; ++k2)
        *reinterpret_cast<f32x4_t*>(&w2l[4 * k2]) =
            *reinterpret_cast<const f32x4_t*>(W2 + (size_t)tid * 48 + 4 * k2);
    const f32x4_t bias2 = *reinterpret_cast<const f32x4_t*>(b2 + tid * 4);

    // ---- finisher: every wave computes the full 16x16 q tile, identical order
    //      (all inputs from LDS, same add order -> bitwise-identical values; the
    //      multi-wave same-value qsh writes are a benign, deterministic race) ----
    {
        f32x4_t r0 = *reinterpret_cast<const f32x4_t*>(&red[0][lane][0]);
        f32x4_t r1 = *reinterpret_cast<const f32x4_t*>(&red[1][lane][0]);
        f32x4_t r2 = *reinterpret_cast<const f32x4_t*>(&red[2][lane][0]);
        f32x4_t r3 = *reinterpret_cast<const f32x4_t*>(&red[3][lane][0]);
        f32x4_t s  = (r0 + r1) + (r2 + r3);
        const float b1n = b1[nc], thn = theta[nc];
#pragma unroll
        for (int j = 0; j < 4; ++j) {
            const int m = g * 4 + j;            // C row (HW-verified C/D layout)
            qsh[m][n] = __cosf(fmaxf(s[j] + b1n, 0.0f) + thn);
        }
    }
    // phase2 reads only slots this wave itself wrote -> same-wave LDS order, no barrier

    // ---------------- phase 2: out = q . W2^T + b2 (streaming) ----------------
    float* orow = out + (size_t)row0 * E + tid * 4;
#pragma unroll 4
    for (int m = 0; m < BM; ++m) {
        if (row0 + m < nrows) {
            float qf[F];
            *reinterpret_cast<f32x4_t*>(&qf[0]) = *reinterpret_cast<const f32x4_t*>(&qsh[m][0]);
            *reinterpret_cast<f32x4_t*>(&qf[4]) = *reinterpret_cast<const f32x4_t*>(&qsh[m][4]);
            *reinterpret_cast<f32x4_t*>(&qf[8]) = *reinterpret_cast<const f32x4_t*>(&qsh[m][8]);

            f32x4_t o;
#pragma unroll
            for (int j = 0; j < 4; ++j) {
                float a = bias2[j];
#pragma unroll
                for (int f = 0; f < F; ++f) a = fmaf(qf[f], w2l[12 * j + f], a);
                o[j] = a;
            }
            __builtin_nontemporal_store(o, reinterpret_cast<f32x4_t*>(orow + (size_t)m * E));
        }
    }
}

extern "C" void kernel_launch(void* const* d_in, const int* in_sizes, int n_in,
                              void* d_out, int out_size, void* d_ws, size_t ws_size,
                              hipStream_t stream)
{
    const float* x     = (const float*)d_in[0];
    const float* W1    = (const float*)d_in[1];
    const float* b1    = (const float*)d_in[2];
    const float* theta = (const float*)d_in[3];
    const float* W2    = (const float*)d_in[4];
    const float* b2    = (const float*)d_in[5];
    float* out = (float*)d_out;

    const int nrows = in_sizes[0] / E;             // B*S = 16384
    const int grid  = (nrows + BM - 1) / BM;       // 1024 blocks, 4 per CU

    ffq_mfma<<<grid, 256, 0, stream>>>(x, W1, b1, theta, W2, b2, out, nrows);
}